// Round 2
// baseline (1012.185 us; speedup 1.0000x reference)
//
#include <hip/hip_runtime.h>
#include <math.h>

#define HEADS 4
#define EPS_BN 1e-5f

__device__ __forceinline__ float lrelu(float x) { return x > 0.f ? x : 0.2f * x; }

// ---------------- edge dtype probe + convert ----------------
// Reference declares edge_index as int64. If the harness hands us int64,
// odd 32-bit words are all high-words == 0 (values < 2^31). Probe and compact.
__global__ void k_detect64(const int* __restrict__ ei, int* flag, int nwords) {
    if (blockIdx.x == 0 && threadIdx.x == 0) {
        int zeros = 0;
        int lim = nwords < 256 ? nwords : 256;
        for (int i = 1; i < lim; i += 2) zeros += (ei[i] == 0);
        *flag = (zeros > lim / 4) ? 1 : 0;
    }
}

__global__ void k_convert(const int* __restrict__ ei, const int* __restrict__ flag,
                          int* __restrict__ out, int n) {
    int i = blockIdx.x * blockDim.x + threadIdx.x;
    int f = *flag;  // uniform
    if (i < n) out[i] = f ? ei[2 * i] : ei[i];
}

// ---------------- CSR build ----------------
__global__ void k_deg_init(int* deg, int N) {
    int i = blockIdx.x * blockDim.x + threadIdx.x;
    if (i < N) deg[i] = 1;  // self loop
}

__global__ void k_deg_count(const int* __restrict__ dst, int* deg, int E) {
    int i = blockIdx.x * blockDim.x + threadIdx.x;
    if (i < E) atomicAdd(&deg[dst[i]], 1);
}

__global__ void k_scan1(const int* __restrict__ deg, int* rowptr, int* bsum, int N) {
    __shared__ int lds[256];
    int t = threadIdx.x, n = blockIdx.x * 256 + t;
    int v = (n < N) ? deg[n] : 0;
    int xv = v;
    lds[t] = xv;
    __syncthreads();
    for (int off = 1; off < 256; off <<= 1) {
        int tmp = (t >= off) ? lds[t - off] : 0;
        __syncthreads();
        xv += tmp;
        lds[t] = xv;
        __syncthreads();
    }
    if (n < N) rowptr[n + 1] = xv;   // partial inclusive scan (pre block offset)
    if (t == 255) bsum[blockIdx.x] = xv;
}

__global__ void k_scan2(int* bsum, int nb) {
    __shared__ int lds[256];
    int t = threadIdx.x;
    int v = (t < nb) ? bsum[t] : 0;
    int xv = v;
    lds[t] = xv;
    __syncthreads();
    for (int off = 1; off < 256; off <<= 1) {
        int tmp = (t >= off) ? lds[t - off] : 0;
        __syncthreads();
        xv += tmp;
        lds[t] = xv;
        __syncthreads();
    }
    if (t < nb) bsum[t] = xv - v;  // exclusive
}

__global__ void k_scan3(int* rowptr, const int* __restrict__ bsum, int N) {
    int n = blockIdx.x * 256 + threadIdx.x;
    if (n < N) rowptr[n + 1] += bsum[blockIdx.x];
    if (n == 0) rowptr[0] = 0;
}

__global__ void k_cursor(const int* __restrict__ rowptr, int* cursor, int N) {
    int n = blockIdx.x * blockDim.x + threadIdx.x;
    if (n < N) cursor[n] = rowptr[n];
}

__global__ void k_scatter(const int* __restrict__ src, const int* __restrict__ dst,
                          int* cursor, int* eidx, int E, int N) {
    int i = blockIdx.x * blockDim.x + threadIdx.x;
    if (i < E) {
        int s = src[i], d = dst[i];
        int pos = atomicAdd(&cursor[d], 1);
        eidx[pos] = s;
    } else if (i < E + N) {
        int n_ = i - E;
        int pos = atomicAdd(&cursor[n_], 1);
        eidx[pos] = n_;  // self loop
    }
}

// ---------------- GEMM: out[N,M] = A[N,128] @ W[128,M] ----------------
// 64x64 tile, BK=32, 4x4 per-thread tile, A transposed in LDS (stride 68 pads banks).
template <int M>
__global__ __launch_bounds__(256) void k_gemm(const float* __restrict__ A,
                                              const float* __restrict__ W,
                                              float* __restrict__ out, int N) {
    __shared__ float Ast[32 * 68];  // [k][row]
    __shared__ float Wst[32 * 68];  // [k][col]
    const int tid = threadIdx.x;
    const int rowbase = blockIdx.x * 64, colbase = blockIdx.y * 64;
    const int tx = tid & 15, ty = tid >> 4;
    const int ar = tid >> 2, ag = tid & 3;        // A staging: row, k-group
    const int wk = tid >> 4, wc = (tid & 15) * 4; // W staging: k (0..15), col (0..60)
    float acc[4][4] = {{0.f, 0.f, 0.f, 0.f}, {0.f, 0.f, 0.f, 0.f},
                       {0.f, 0.f, 0.f, 0.f}, {0.f, 0.f, 0.f, 0.f}};
    const int arow = min(rowbase + ar, N - 1);

    for (int k0 = 0; k0 < 128; k0 += 32) {
        const float* Ap = A + (size_t)arow * 128 + k0 + ag * 4;
        float4 a0 = *(const float4*)Ap;
        float4 a1 = *(const float4*)(Ap + 16);
        // W tile: 32 k x 64 cols = 2048 floats; each of 256 threads stages TWO float4s.
        float4 wv0 = *(const float4*)(W + (size_t)(k0 + wk) * M + colbase + wc);
        float4 wv1 = *(const float4*)(W + (size_t)(k0 + wk + 16) * M + colbase + wc);
#pragma unroll
        for (int j = 0; j < 4; j++) {
            Ast[(ag * 4 + j) * 68 + ar] = ((const float*)&a0)[j];
            Ast[((ag + 4) * 4 + j) * 68 + ar] = ((const float*)&a1)[j];
        }
        *(float4*)&Wst[wk * 68 + wc] = wv0;
        *(float4*)&Wst[(wk + 16) * 68 + wc] = wv1;
        __syncthreads();
#pragma unroll
        for (int k = 0; k < 32; k++) {
            float4 av = *(const float4*)&Ast[k * 68 + ty * 4];
            float4 wv2 = *(const float4*)&Wst[k * 68 + tx * 4];
#pragma unroll
            for (int i = 0; i < 4; i++)
#pragma unroll
                for (int j = 0; j < 4; j++)
                    acc[i][j] += ((const float*)&av)[i] * ((const float*)&wv2)[j];
        }
        __syncthreads();
    }
#pragma unroll
    for (int i = 0; i < 4; i++) {
        int r = rowbase + ty * 4 + i;
        if (r < N)
            *(float4*)&out[(size_t)r * M + colbase + tx * 4] =
                make_float4(acc[i][0], acc[i][1], acc[i][2], acc[i][3]);
    }
}

// ---------------- attention scores: a_s[n,h] = sum_c xp[n,h,c]*att_s[h,c] ----------------
// one wave per node. att arrays are flat [H*C]; idx = h*C+c maps directly.
template <int C>
__global__ void k_att(const float* __restrict__ xp, const float* __restrict__ att_s,
                      const float* __restrict__ att_d, float* __restrict__ a_s,
                      float* __restrict__ a_d, int N) {
    int wid = (blockIdx.x * blockDim.x + threadIdx.x) >> 6;
    int lane = threadIdx.x & 63;
    if (wid >= N) return;
    if (C == 32) {
        const float* xr = xp + (size_t)wid * 128;
        float x0 = xr[lane], x1 = xr[lane + 64];
        float ps0 = x0 * att_s[lane], ps1 = x1 * att_s[lane + 64];
        float pd0 = x0 * att_d[lane], pd1 = x1 * att_d[lane + 64];
        for (int m = 16; m >= 1; m >>= 1) {
            ps0 += __shfl_xor(ps0, m, 64);
            ps1 += __shfl_xor(ps1, m, 64);
            pd0 += __shfl_xor(pd0, m, 64);
            pd1 += __shfl_xor(pd1, m, 64);
        }
        if ((lane & 31) == 0) {
            int h = lane >> 5;
            a_s[wid * 4 + h] = ps0;
            a_s[wid * 4 + 2 + h] = ps1;
            a_d[wid * 4 + h] = pd0;
            a_d[wid * 4 + 2 + h] = pd1;
        }
    } else {  // C == 128
        const float* xr = xp + (size_t)wid * 512;
        float ts[4], td[4];
#pragma unroll
        for (int h = 0; h < 4; h++) {
            float xa = xr[h * 128 + lane], xb = xr[h * 128 + 64 + lane];
            ts[h] = xa * att_s[h * 128 + lane] + xb * att_s[h * 128 + 64 + lane];
            td[h] = xa * att_d[h * 128 + lane] + xb * att_d[h * 128 + 64 + lane];
        }
        for (int m = 32; m >= 1; m >>= 1) {
#pragma unroll
            for (int h = 0; h < 4; h++) {
                ts[h] += __shfl_xor(ts[h], m, 64);
                td[h] += __shfl_xor(td[h], m, 64);
            }
        }
        if (lane == 0) {
#pragma unroll
            for (int h = 0; h < 4; h++) {
                a_s[wid * 4 + h] = ts[h];
                a_d[wid * 4 + h] = td[h];
            }
        }
    }
}

// ---------------- aggregation, layers 0/1 (concat): one wave per dst node ----------------
__global__ void k_agg01(const float* __restrict__ xp, const float* __restrict__ a_s,
                        const float* __restrict__ a_d, const int* __restrict__ rowptr,
                        const int* __restrict__ eidx, const float* __restrict__ bias,
                        float* __restrict__ out, int N) {
    int d = (blockIdx.x * blockDim.x + threadIdx.x) >> 6;
    int lane = threadIdx.x & 63;
    if (d >= N) return;
    int h0 = lane >> 5;  // lanes 0-31: heads 0/2; lanes 32-63: heads 1/3
    float ad0 = a_d[d * 4 + h0], ad1 = a_d[d * 4 + 2 + h0];
    int jb = rowptr[d], je = rowptr[d + 1];
    float m0 = -INFINITY, m1 = -INFINITY;
    float den0 = 0.f, den1 = 0.f, acc0 = 0.f, acc1 = 0.f;
    for (int j = jb; j < je; ++j) {
        int s = __builtin_amdgcn_readfirstlane(eidx[j]);
        float e0 = lrelu(a_s[s * 4 + h0] + ad0);
        float e1 = lrelu(a_s[s * 4 + 2 + h0] + ad1);
        float x0 = xp[(size_t)s * 128 + lane];
        float x1 = xp[(size_t)s * 128 + 64 + lane];
        if (e0 <= m0) { float p = __expf(e0 - m0); den0 += p; acc0 += p * x0; }
        else { float sc = __expf(m0 - e0); den0 = den0 * sc + 1.f; acc0 = acc0 * sc + x0; m0 = e0; }
        if (e1 <= m1) { float p = __expf(e1 - m1); den1 += p; acc1 += p * x1; }
        else { float sc = __expf(m1 - e1); den1 = den1 * sc + 1.f; acc1 = acc1 * sc + x1; m1 = e1; }
    }
    out[(size_t)d * 128 + lane] = acc0 / (den0 + 1e-16f) + bias[lane];
    out[(size_t)d * 128 + 64 + lane] = acc1 / (den1 + 1e-16f) + bias[64 + lane];
}

// ---------------- aggregation, layer 2 (head-mean): one wave per dst node ----------------
__global__ void k_agg2(const float* __restrict__ xp, const float* __restrict__ a_s,
                       const float* __restrict__ a_d, const int* __restrict__ rowptr,
                       const int* __restrict__ eidx, const float* __restrict__ bias,
                       float* __restrict__ out, int N) {
    int d = (blockIdx.x * blockDim.x + threadIdx.x) >> 6;
    int lane = threadIdx.x & 63;
    if (d >= N) return;
    float4 ad4 = *(const float4*)(a_d + (size_t)d * 4);
    int jb = rowptr[d], je = rowptr[d + 1];
    float m[4] = {-INFINITY, -INFINITY, -INFINITY, -INFINITY};
    float den[4] = {0.f, 0.f, 0.f, 0.f};
    float acc[8] = {0.f, 0.f, 0.f, 0.f, 0.f, 0.f, 0.f, 0.f};
    for (int j = jb; j < je; ++j) {
        int s = __builtin_amdgcn_readfirstlane(eidx[j]);
        float4 as4 = *(const float4*)(a_s + (size_t)s * 4);
        float sc[4], p[4];
#pragma unroll
        for (int h = 0; h < 4; h++) {
            float e = lrelu(((const float*)&as4)[h] + ((const float*)&ad4)[h]);
            if (e <= m[h]) { p[h] = __expf(e - m[h]); sc[h] = 1.f; den[h] += p[h]; }
            else { sc[h] = __expf(m[h] - e); p[h] = 1.f; den[h] = den[h] * sc[h] + 1.f; m[h] = e; }
        }
        const float* xr = xp + (size_t)s * 512 + lane;
#pragma unroll
        for (int i = 0; i < 8; i++) {
            float x = xr[i * 64];
            int h = i >> 1;  // idx = i*64+lane; head = idx>>7
            acc[i] = acc[i] * sc[h] + p[h] * x;
        }
    }
    float v0 = 0.f, v1 = 0.f;
#pragma unroll
    for (int h = 0; h < 4; h++) {
        float inv = 1.f / (den[h] + 1e-16f);
        v0 += acc[2 * h] * inv;       // c = lane
        v1 += acc[2 * h + 1] * inv;   // c = lane + 64
    }
    out[(size_t)d * 128 + lane] = 0.25f * v0 + bias[lane];
    out[(size_t)d * 128 + 64 + lane] = 0.25f * v1 + bias[64 + lane];
}

// ---------------- batch norm ----------------
__global__ void k_bnstats(const float* __restrict__ x, float* __restrict__ sums, int N) {
    int col = threadIdx.x & 127, half = threadIdx.x >> 7;
    float s1 = 0.f, s2 = 0.f;
    for (int r = blockIdx.x * 2 + half; r < N; r += gridDim.x * 2) {
        float v = x[(size_t)r * 128 + col];
        s1 += v;
        s2 += v * v;
    }
    atomicAdd(&sums[col], s1);
    atomicAdd(&sums[128 + col], s2);
}

__global__ void k_bnapply(float* __restrict__ x, const float* __restrict__ sums,
                          const float* __restrict__ gamma, const float* __restrict__ beta,
                          int N, int elu) {
    int idx = blockIdx.x * blockDim.x + threadIdx.x;  // float4 index
    if (idx >= N * 32) return;
    float4 v = ((float4*)x)[idx];
    int colb = (idx & 31) * 4;
    float invN = 1.f / (float)N;
#pragma unroll
    for (int j = 0; j < 4; j++) {
        int col = colb + j;
        float mu = sums[col] * invN;
        float var = sums[128 + col] * invN - mu * mu;
        float y = (((float*)&v)[j] - mu) * rsqrtf(var + EPS_BN) * gamma[col] + beta[col];
        if (elu) y = y > 0.f ? y : __expf(y) - 1.f;
        ((float*)&v)[j] = y;
    }
    ((float4*)x)[idx] = v;
}

// ---------------- launch ----------------
extern "C" void kernel_launch(void* const* d_in, const int* in_sizes, int n_in,
                              void* d_out, int out_size, void* d_ws, size_t ws_size,
                              hipStream_t stream) {
    const float* x = (const float*)d_in[0];
    const int* ei_raw = (const int*)d_in[1];
    const float* W0 = (const float*)d_in[2];
    const float* as0 = (const float*)d_in[3];
    const float* ad0 = (const float*)d_in[4];
    const float* b0 = (const float*)d_in[5];
    const float* g0 = (const float*)d_in[6];
    const float* be0 = (const float*)d_in[7];
    const float* W1 = (const float*)d_in[8];
    const float* as1 = (const float*)d_in[9];
    const float* ad1 = (const float*)d_in[10];
    const float* b1 = (const float*)d_in[11];
    const float* g1 = (const float*)d_in[12];
    const float* be1 = (const float*)d_in[13];
    const float* W2 = (const float*)d_in[14];
    const float* as2 = (const float*)d_in[15];
    const float* ad2 = (const float*)d_in[16];
    const float* b2 = (const float*)d_in[17];
    const float* g2v = (const float*)d_in[18];
    const float* be2 = (const float*)d_in[19];

    const int N = in_sizes[0] / 128;
    const int E = in_sizes[1] / 2;

    // workspace carve (256B aligned)
    char* p = (char*)d_ws;
    auto alloc = [&](size_t bytes) {
        void* r = (void*)p;
        p += (bytes + 255) & ~(size_t)255;
        return r;
    };
    float* xp = (float*)alloc((size_t)N * 512 * 4);    // 102.4 MB (layer2; layers0/1 use first quarter)
    float* hbuf = (float*)alloc((size_t)N * 128 * 4);  // 25.6 MB
    float* As = (float*)alloc((size_t)N * 4 * 4);
    float* Ad = (float*)alloc((size_t)N * 4 * 4);
    int* deg = (int*)alloc((size_t)N * 4);
    int* rowptr = (int*)alloc((size_t)(N + 1) * 4);
    int* cursor = (int*)alloc((size_t)N * 4);
    int* bsum = (int*)alloc(1024);
    int* eidx = (int*)alloc((size_t)(E + N) * 4);
    float* bns = (float*)alloc(256 * 4);
    int* ei32 = (int*)alloc((size_t)2 * E * 4);  // converted src|dst
    int* flag = (int*)alloc(256);
    if ((size_t)(p - (char*)d_ws) > ws_size) return;  // ws too small: fail loudly, not corruptly

    const int nb = (N + 255) / 256;
    const int gw = (N + 3) / 4;  // wave-per-node kernels: 4 waves/block
    dim3 gg1((N + 63) / 64, 2), gg2((N + 63) / 64, 8);

    // --- edge dtype normalize (int64 vs int32) ---
    k_detect64<<<1, 64, 0, stream>>>(ei_raw, flag, 2 * E);
    k_convert<<<(2 * E + 255) / 256, 256, 0, stream>>>(ei_raw, flag, ei32, 2 * E);
    const int* srcv = ei32;
    const int* dstv = ei32 + E;

    // --- CSR build (per call; ws is re-poisoned every timed iteration) ---
    k_deg_init<<<nb, 256, 0, stream>>>(deg, N);
    k_deg_count<<<(E + 255) / 256, 256, 0, stream>>>(dstv, deg, E);
    k_scan1<<<nb, 256, 0, stream>>>(deg, rowptr, bsum, N);
    k_scan2<<<1, 256, 0, stream>>>(bsum, nb);
    k_scan3<<<nb, 256, 0, stream>>>(rowptr, bsum, N);
    k_cursor<<<nb, 256, 0, stream>>>(rowptr, cursor, N);
    k_scatter<<<(E + N + 255) / 256, 256, 0, stream>>>(srcv, dstv, cursor, eidx, E, N);

    // --- layer 0: in(128) -> 4 heads x 32, concat ---
    k_gemm<128><<<gg1, 256, 0, stream>>>(x, W0, xp, N);
    k_att<32><<<gw, 256, 0, stream>>>(xp, as0, ad0, As, Ad, N);
    k_agg01<<<gw, 256, 0, stream>>>(xp, As, Ad, rowptr, eidx, b0, hbuf, N);
    hipMemsetAsync(bns, 0, 256 * 4, stream);
    k_bnstats<<<256, 256, 0, stream>>>(hbuf, bns, N);
    k_bnapply<<<(N * 32 + 255) / 256, 256, 0, stream>>>(hbuf, bns, g0, be0, N, 1);

    // --- layer 1: 128 -> 4 heads x 32, concat ---
    k_gemm<128><<<gg1, 256, 0, stream>>>(hbuf, W1, xp, N);
    k_att<32><<<gw, 256, 0, stream>>>(xp, as1, ad1, As, Ad, N);
    k_agg01<<<gw, 256, 0, stream>>>(xp, As, Ad, rowptr, eidx, b1, hbuf, N);
    hipMemsetAsync(bns, 0, 256 * 4, stream);
    k_bnstats<<<256, 256, 0, stream>>>(hbuf, bns, N);
    k_bnapply<<<(N * 32 + 255) / 256, 256, 0, stream>>>(hbuf, bns, g1, be1, N, 1);

    // --- layer 2: 128 -> 4 heads x 128, mean over heads ---
    float* outf = (float*)d_out;
    k_gemm<512><<<gg2, 256, 0, stream>>>(hbuf, W2, xp, N);
    k_att<128><<<gw, 256, 0, stream>>>(xp, as2, ad2, As, Ad, N);
    k_agg2<<<gw, 256, 0, stream>>>(xp, As, Ad, rowptr, eidx, b2, outf, N);
    hipMemsetAsync(bns, 0, 256 * 4, stream);
    k_bnstats<<<256, 256, 0, stream>>>(outf, bns, N);
    k_bnapply<<<(N * 32 + 255) / 256, 256, 0, stream>>>(outf, bns, g2v, be2, N, 0);
}

// Round 3
// 898.615 us; speedup vs baseline: 1.1264x; 1.1264x over previous
//
#include <hip/hip_runtime.h>
#include <math.h>

#define HEADS 4
#define EPS_BN 1e-5f

__device__ __forceinline__ float lrelu(float x) { return x > 0.f ? x : 0.2f * x; }

// ---------------- edge dtype probe + convert ----------------
// Reference declares edge_index as int64. If the harness hands us int64,
// odd 32-bit words are all high-words == 0 (values < 2^31). Probe and compact.
__global__ void k_detect64(const int* __restrict__ ei, int* flag, int nwords) {
    if (blockIdx.x == 0 && threadIdx.x == 0) {
        int zeros = 0;
        int lim = nwords < 256 ? nwords : 256;
        for (int i = 1; i < lim; i += 2) zeros += (ei[i] == 0);
        *flag = (zeros > lim / 4) ? 1 : 0;
    }
}

__global__ void k_convert(const int* __restrict__ ei, const int* __restrict__ flag,
                          int* __restrict__ out, int n) {
    int i = blockIdx.x * blockDim.x + threadIdx.x;
    int f = *flag;  // uniform
    if (i < n) out[i] = f ? ei[2 * i] : ei[i];
}

// ---------------- CSR build ----------------
__global__ void k_deg_init(int* deg, int N) {
    int i = blockIdx.x * blockDim.x + threadIdx.x;
    if (i < N) deg[i] = 1;  // self loop
}

__global__ void k_deg_count(const int* __restrict__ dst, int* deg, int E) {
    int i = blockIdx.x * blockDim.x + threadIdx.x;
    if (i < E) atomicAdd(&deg[dst[i]], 1);
}

__global__ void k_scan1(const int* __restrict__ deg, int* rowptr, int* bsum, int N) {
    __shared__ int lds[256];
    int t = threadIdx.x, n = blockIdx.x * 256 + t;
    int v = (n < N) ? deg[n] : 0;
    int xv = v;
    lds[t] = xv;
    __syncthreads();
    for (int off = 1; off < 256; off <<= 1) {
        int tmp = (t >= off) ? lds[t - off] : 0;
        __syncthreads();
        xv += tmp;
        lds[t] = xv;
        __syncthreads();
    }
    if (n < N) rowptr[n + 1] = xv;   // partial inclusive scan (pre block offset)
    if (t == 255) bsum[blockIdx.x] = xv;
}

__global__ void k_scan2(int* bsum, int nb) {
    __shared__ int lds[256];
    int t = threadIdx.x;
    int v = (t < nb) ? bsum[t] : 0;
    int xv = v;
    lds[t] = xv;
    __syncthreads();
    for (int off = 1; off < 256; off <<= 1) {
        int tmp = (t >= off) ? lds[t - off] : 0;
        __syncthreads();
        xv += tmp;
        lds[t] = xv;
        __syncthreads();
    }
    if (t < nb) bsum[t] = xv - v;  // exclusive
}

__global__ void k_scan3(int* rowptr, const int* __restrict__ bsum, int N) {
    int n = blockIdx.x * 256 + threadIdx.x;
    if (n < N) rowptr[n + 1] += bsum[blockIdx.x];
    if (n == 0) rowptr[0] = 0;
}

__global__ void k_cursor(const int* __restrict__ rowptr, int* cursor, int N) {
    int n = blockIdx.x * blockDim.x + threadIdx.x;
    if (n < N) cursor[n] = rowptr[n];
}

__global__ void k_scatter(const int* __restrict__ src, const int* __restrict__ dst,
                          int* cursor, int* eidx, int E, int N) {
    int i = blockIdx.x * blockDim.x + threadIdx.x;
    if (i < E) {
        int s = src[i], d = dst[i];
        int pos = atomicAdd(&cursor[d], 1);
        eidx[pos] = s;
    } else if (i < E + N) {
        int n_ = i - E;
        int pos = atomicAdd(&cursor[n_], 1);
        eidx[pos] = n_;  // self loop
    }
}

// ---------------- GEMM: out[N,M] = A[N,K] @ W[K,M] ----------------
// 64x64 tile, BK=32, 4x4 per-thread tile, A transposed in LDS (stride 68 pads banks).
template <int M, int K>
__global__ __launch_bounds__(256) void k_gemm(const float* __restrict__ A,
                                              const float* __restrict__ W,
                                              float* __restrict__ out, int N) {
    __shared__ float Ast[32 * 68];  // [k][row]
    __shared__ float Wst[32 * 68];  // [k][col]
    const int tid = threadIdx.x;
    const int rowbase = blockIdx.x * 64, colbase = blockIdx.y * 64;
    const int tx = tid & 15, ty = tid >> 4;
    const int ar = tid >> 2, ag = tid & 3;        // A staging: row, k-group
    const int wk = tid >> 4, wc = (tid & 15) * 4; // W staging: k (0..15), col (0..60)
    float acc[4][4] = {{0.f, 0.f, 0.f, 0.f}, {0.f, 0.f, 0.f, 0.f},
                       {0.f, 0.f, 0.f, 0.f}, {0.f, 0.f, 0.f, 0.f}};
    const int arow = min(rowbase + ar, N - 1);

    for (int k0 = 0; k0 < K; k0 += 32) {
        const float* Ap = A + (size_t)arow * K + k0 + ag * 4;
        float4 a0 = *(const float4*)Ap;
        float4 a1 = *(const float4*)(Ap + 16);
        // W tile: 32 k x 64 cols = 2048 floats; each of 256 threads stages TWO float4s.
        float4 wv0 = *(const float4*)(W + (size_t)(k0 + wk) * M + colbase + wc);
        float4 wv1 = *(const float4*)(W + (size_t)(k0 + wk + 16) * M + colbase + wc);
#pragma unroll
        for (int j = 0; j < 4; j++) {
            Ast[(ag * 4 + j) * 68 + ar] = ((const float*)&a0)[j];
            Ast[((ag + 4) * 4 + j) * 68 + ar] = ((const float*)&a1)[j];
        }
        *(float4*)&Wst[wk * 68 + wc] = wv0;
        *(float4*)&Wst[(wk + 16) * 68 + wc] = wv1;
        __syncthreads();
#pragma unroll
        for (int k = 0; k < 32; k++) {
            float4 av = *(const float4*)&Ast[k * 68 + ty * 4];
            float4 wv2 = *(const float4*)&Wst[k * 68 + tx * 4];
#pragma unroll
            for (int i = 0; i < 4; i++)
#pragma unroll
                for (int j = 0; j < 4; j++)
                    acc[i][j] += ((const float*)&av)[i] * ((const float*)&wv2)[j];
        }
        __syncthreads();
    }
#pragma unroll
    for (int i = 0; i < 4; i++) {
        int r = rowbase + ty * 4 + i;
        if (r < N)
            *(float4*)&out[(size_t)r * M + colbase + tx * 4] =
                make_float4(acc[i][0], acc[i][1], acc[i][2], acc[i][3]);
    }
}

// ---------------- attention scores, layers 0/1: a_s[n,h]=sum_c xp[n,h,c]*att[h,c] ----------------
// one wave per node; C=32, att flat [128].
__global__ void k_att32(const float* __restrict__ xp, const float* __restrict__ att_s,
                        const float* __restrict__ att_d, float* __restrict__ a_s,
                        float* __restrict__ a_d, int N) {
    int wid = (blockIdx.x * blockDim.x + threadIdx.x) >> 6;
    int lane = threadIdx.x & 63;
    if (wid >= N) return;
    const float* xr = xp + (size_t)wid * 128;
    float x0 = xr[lane], x1 = xr[lane + 64];
    float ps0 = x0 * att_s[lane], ps1 = x1 * att_s[lane + 64];
    float pd0 = x0 * att_d[lane], pd1 = x1 * att_d[lane + 64];
    for (int m = 16; m >= 1; m >>= 1) {
        ps0 += __shfl_xor(ps0, m, 64);
        ps1 += __shfl_xor(ps1, m, 64);
        pd0 += __shfl_xor(pd0, m, 64);
        pd1 += __shfl_xor(pd1, m, 64);
    }
    if ((lane & 31) == 0) {
        int h = lane >> 5;
        a_s[wid * 4 + h] = ps0;
        a_s[wid * 4 + 2 + h] = ps1;
        a_d[wid * 4 + h] = pd0;
        a_d[wid * 4 + 2 + h] = pd1;
    }
}

// ---------------- layer 2 score precompute: w~[h,k] = sum_c W2[k,h*128+c]*att[h,c] ----------------
// Wt layout: [0..511]=src-heads (h*128+k), [512..1023]=dst-heads. 1024 waves.
__global__ void k_makeWt(const float* __restrict__ W2, const float* __restrict__ as2,
                         const float* __restrict__ ad2, float* __restrict__ Wt) {
    int wid = (blockIdx.x * blockDim.x + threadIdx.x) >> 6;
    int lane = threadIdx.x & 63;
    if (wid >= 1024) return;
    int k = wid & 127, hh = (wid >> 7) & 3, isd = wid >> 9;
    const float* att = isd ? ad2 : as2;
    float v = W2[(size_t)k * 512 + hh * 128 + lane] * att[hh * 128 + lane] +
              W2[(size_t)k * 512 + hh * 128 + 64 + lane] * att[hh * 128 + 64 + lane];
    for (int m = 32; m >= 1; m >>= 1) v += __shfl_xor(v, m, 64);
    if (lane == 0) Wt[isd * 512 + hh * 128 + k] = v;
}

// ---------------- layer 2 scores from h (no xp needed): a_s[n,h] = h[n]·w~_s[h] ----------------
__global__ void k_attW(const float* __restrict__ hb, const float* __restrict__ Wt,
                       float* __restrict__ a_s, float* __restrict__ a_d, int N) {
    int wid = (blockIdx.x * blockDim.x + threadIdx.x) >> 6;
    int lane = threadIdx.x & 63;
    if (wid >= N) return;
    float x0 = hb[(size_t)wid * 128 + lane], x1 = hb[(size_t)wid * 128 + 64 + lane];
    float ts[4], td[4];
#pragma unroll
    for (int hh = 0; hh < 4; hh++) {
        ts[hh] = x0 * Wt[hh * 128 + lane] + x1 * Wt[hh * 128 + 64 + lane];
        td[hh] = x0 * Wt[512 + hh * 128 + lane] + x1 * Wt[512 + hh * 128 + 64 + lane];
    }
    for (int m = 32; m >= 1; m >>= 1) {
#pragma unroll
        for (int hh = 0; hh < 4; hh++) {
            ts[hh] += __shfl_xor(ts[hh], m, 64);
            td[hh] += __shfl_xor(td[hh], m, 64);
        }
    }
    if (lane == 0) {
#pragma unroll
        for (int hh = 0; hh < 4; hh++) {
            a_s[wid * 4 + hh] = ts[hh];
            a_d[wid * 4 + hh] = td[hh];
        }
    }
}

// ---------------- aggregation, layers 0/1 (concat): one wave per dst node ----------------
// lane handles channels 2*lane, 2*lane+1 — both belong to head lane>>4.
// Branchless online softmax (no divergent rescale path).
__global__ void k_agg01(const float* __restrict__ xp, const float* __restrict__ a_s,
                        const float* __restrict__ a_d, const int* __restrict__ rowptr,
                        const int* __restrict__ eidx, const float* __restrict__ bias,
                        float* __restrict__ out, int N) {
    int d = (blockIdx.x * blockDim.x + threadIdx.x) >> 6;
    int lane = threadIdx.x & 63;
    if (d >= N) return;
    int hh = lane >> 4;
    float ad = a_d[(size_t)d * 4 + hh];
    int jb = rowptr[d], je = rowptr[d + 1];
    float m = -INFINITY, den = 0.f, a0 = 0.f, a1 = 0.f;
    for (int j = jb; j < je; ++j) {
        int s = __builtin_amdgcn_readfirstlane(eidx[j]);
        float e = lrelu(a_s[(size_t)s * 4 + hh] + ad);
        float2 xv = *(const float2*)(xp + (size_t)s * 128 + 2 * lane);
        float nm = fmaxf(m, e);
        float sc = __expf(m - nm);
        float p = __expf(e - nm);
        den = den * sc + p;
        m = nm;
        a0 = a0 * sc + p * xv.x;
        a1 = a1 * sc + p * xv.y;
    }
    float inv = 1.f / (den + 1e-16f);
    float2 o = make_float2(a0 * inv + bias[2 * lane], a1 * inv + bias[2 * lane + 1]);
    *(float2*)(out + (size_t)d * 128 + 2 * lane) = o;
}

// ---------------- aggregation, layer 2: agg[d,h,:] = sum_e alpha_eh * h[src_e,:] ----------------
// Gathers only the 128-dim h row per edge (512 B) and reuses it across 4 heads.
__global__ void k_aggL2(const float* __restrict__ hb, const float* __restrict__ a_s,
                        const float* __restrict__ a_d, const int* __restrict__ rowptr,
                        const int* __restrict__ eidx, float* __restrict__ aggbuf, int N) {
    int d = (blockIdx.x * blockDim.x + threadIdx.x) >> 6;
    int lane = threadIdx.x & 63;
    if (d >= N) return;
    float4 ad4 = *(const float4*)(a_d + (size_t)d * 4);
    int jb = rowptr[d], je = rowptr[d + 1];
    float m[4] = {-INFINITY, -INFINITY, -INFINITY, -INFINITY};
    float den[4] = {0.f, 0.f, 0.f, 0.f};
    float acc[4][2] = {{0.f, 0.f}, {0.f, 0.f}, {0.f, 0.f}, {0.f, 0.f}};
    for (int j = jb; j < je; ++j) {
        int s = __builtin_amdgcn_readfirstlane(eidx[j]);
        float4 as4 = *(const float4*)(a_s + (size_t)s * 4);
        float2 xv = *(const float2*)(hb + (size_t)s * 128 + 2 * lane);
        float p[4], sc[4];
#pragma unroll
        for (int hh = 0; hh < 4; hh++) {
            float e = lrelu(((const float*)&as4)[hh] + ((const float*)&ad4)[hh]);
            float nm = fmaxf(m[hh], e);
            sc[hh] = __expf(m[hh] - nm);
            p[hh] = __expf(e - nm);
            den[hh] = den[hh] * sc[hh] + p[hh];
            m[hh] = nm;
        }
#pragma unroll
        for (int hh = 0; hh < 4; hh++) {
            acc[hh][0] = acc[hh][0] * sc[hh] + p[hh] * xv.x;
            acc[hh][1] = acc[hh][1] * sc[hh] + p[hh] * xv.y;
        }
    }
#pragma unroll
    for (int hh = 0; hh < 4; hh++) {
        float inv = 1.f / (den[hh] + 1e-16f);
        float2 o = make_float2(acc[hh][0] * inv, acc[hh][1] * inv);
        *(float2*)(aggbuf + (size_t)d * 512 + hh * 128 + 2 * lane) = o;
    }
}

// ---------------- W2 reshuffle: W2p[h*128+k, c] = 0.25 * W2[k, h*128+c] ----------------
// Folds the head-mean. (b2 is omitted: a per-column constant shift is exactly
// cancelled by the following BatchNorm's mean subtraction.)
__global__ void k_w2p(const float* __restrict__ W2, float* __restrict__ W2p) {
    int idx = blockIdx.x * blockDim.x + threadIdx.x;
    if (idx >= 512 * 128) return;
    int j = idx >> 7, c = idx & 127;
    W2p[idx] = 0.25f * W2[(size_t)(j & 127) * 512 + (j >> 7) * 128 + c];
}

// ---------------- batch norm ----------------
__global__ void k_bnstats(const float* __restrict__ x, float* __restrict__ sums, int N) {
    int col = threadIdx.x & 127, half = threadIdx.x >> 7;
    float s1 = 0.f, s2 = 0.f;
    for (int r = blockIdx.x * 2 + half; r < N; r += gridDim.x * 2) {
        float v = x[(size_t)r * 128 + col];
        s1 += v;
        s2 += v * v;
    }
    atomicAdd(&sums[col], s1);
    atomicAdd(&sums[128 + col], s2);
}

__global__ void k_bnapply(float* __restrict__ x, const float* __restrict__ sums,
                          const float* __restrict__ gamma, const float* __restrict__ beta,
                          int N, int elu) {
    int idx = blockIdx.x * blockDim.x + threadIdx.x;  // float4 index
    if (idx >= N * 32) return;
    float4 v = ((float4*)x)[idx];
    int colb = (idx & 31) * 4;
    float invN = 1.f / (float)N;
#pragma unroll
    for (int j = 0; j < 4; j++) {
        int col = colb + j;
        float mu = sums[col] * invN;
        float var = sums[128 + col] * invN - mu * mu;
        float y = (((float*)&v)[j] - mu) * rsqrtf(var + EPS_BN) * gamma[col] + beta[col];
        if (elu) y = y > 0.f ? y : __expf(y) - 1.f;
        ((float*)&v)[j] = y;
    }
    ((float4*)x)[idx] = v;
}

// ---------------- launch ----------------
extern "C" void kernel_launch(void* const* d_in, const int* in_sizes, int n_in,
                              void* d_out, int out_size, void* d_ws, size_t ws_size,
                              hipStream_t stream) {
    const float* x = (const float*)d_in[0];
    const int* ei_raw = (const int*)d_in[1];
    const float* W0 = (const float*)d_in[2];
    const float* as0 = (const float*)d_in[3];
    const float* ad0 = (const float*)d_in[4];
    const float* b0 = (const float*)d_in[5];
    const float* g0 = (const float*)d_in[6];
    const float* be0 = (const float*)d_in[7];
    const float* W1 = (const float*)d_in[8];
    const float* as1 = (const float*)d_in[9];
    const float* ad1 = (const float*)d_in[10];
    const float* b1 = (const float*)d_in[11];
    const float* g1 = (const float*)d_in[12];
    const float* be1 = (const float*)d_in[13];
    const float* W2 = (const float*)d_in[14];
    const float* as2 = (const float*)d_in[15];
    const float* ad2 = (const float*)d_in[16];
    const float* g2v = (const float*)d_in[18];
    const float* be2 = (const float*)d_in[19];

    const int N = in_sizes[0] / 128;
    const int E = in_sizes[1] / 2;

    // workspace carve (256B aligned)
    char* p = (char*)d_ws;
    auto alloc = [&](size_t bytes) {
        void* r = (void*)p;
        p += (bytes + 255) & ~(size_t)255;
        return r;
    };
    float* xp = (float*)alloc((size_t)N * 512 * 4);    // layers 0/1: xp (N*128); layer 2: aggbuf (N*512)
    float* hbuf = (float*)alloc((size_t)N * 128 * 4);  // 25.6 MB
    float* As = (float*)alloc((size_t)N * 4 * 4);
    float* Ad = (float*)alloc((size_t)N * 4 * 4);
    int* deg = (int*)alloc((size_t)N * 4);
    int* rowptr = (int*)alloc((size_t)(N + 1) * 4);
    int* cursor = (int*)alloc((size_t)N * 4);
    int* bsum = (int*)alloc(1024);
    int* eidx = (int*)alloc((size_t)(E + N) * 4);
    float* bns = (float*)alloc(256 * 4);
    int* ei32 = (int*)alloc((size_t)2 * E * 4);  // converted src|dst
    int* flag = (int*)alloc(256);
    float* Wt = (float*)alloc(1024 * 4);
    float* W2p = (float*)alloc((size_t)512 * 128 * 4);
    if ((size_t)(p - (char*)d_ws) > ws_size) return;  // ws too small: fail loudly, not corruptly

    const int nb = (N + 255) / 256;
    const int gw = (N + 3) / 4;  // wave-per-node kernels: 4 waves/block
    dim3 gg1((N + 63) / 64, 2);

    // --- edge dtype normalize (int64 vs int32) ---
    k_detect64<<<1, 64, 0, stream>>>(ei_raw, flag, 2 * E);
    k_convert<<<(2 * E + 255) / 256, 256, 0, stream>>>(ei_raw, flag, ei32, 2 * E);
    const int* srcv = ei32;
    const int* dstv = ei32 + E;

    // --- CSR build (per call; ws is re-poisoned every timed iteration) ---
    k_deg_init<<<nb, 256, 0, stream>>>(deg, N);
    k_deg_count<<<(E + 255) / 256, 256, 0, stream>>>(dstv, deg, E);
    k_scan1<<<nb, 256, 0, stream>>>(deg, rowptr, bsum, N);
    k_scan2<<<1, 256, 0, stream>>>(bsum, nb);
    k_scan3<<<nb, 256, 0, stream>>>(rowptr, bsum, N);
    k_cursor<<<nb, 256, 0, stream>>>(rowptr, cursor, N);
    k_scatter<<<(E + N + 255) / 256, 256, 0, stream>>>(srcv, dstv, cursor, eidx, E, N);

    // --- layer 0: in(128) -> 4 heads x 32, concat ---
    k_gemm<128, 128><<<gg1, 256, 0, stream>>>(x, W0, xp, N);
    k_att32<<<gw, 256, 0, stream>>>(xp, as0, ad0, As, Ad, N);
    k_agg01<<<gw, 256, 0, stream>>>(xp, As, Ad, rowptr, eidx, b0, hbuf, N);
    hipMemsetAsync(bns, 0, 256 * 4, stream);
    k_bnstats<<<256, 256, 0, stream>>>(hbuf, bns, N);
    k_bnapply<<<(N * 32 + 255) / 256, 256, 0, stream>>>(hbuf, bns, g0, be0, N, 1);

    // --- layer 1: 128 -> 4 heads x 32, concat ---
    k_gemm<128, 128><<<gg1, 256, 0, stream>>>(hbuf, W1, xp, N);
    k_att32<<<gw, 256, 0, stream>>>(xp, as1, ad1, As, Ad, N);
    k_agg01<<<gw, 256, 0, stream>>>(xp, As, Ad, rowptr, eidx, b1, hbuf, N);
    hipMemsetAsync(bns, 0, 256 * 4, stream);
    k_bnstats<<<256, 256, 0, stream>>>(hbuf, bns, N);
    k_bnapply<<<(N * 32 + 255) / 256, 256, 0, stream>>>(hbuf, bns, g1, be1, N, 1);

    // --- layer 2: 128 -> 4 heads x 128, mean over heads ---
    // Linearity: scores a = h·(W2_h @ att_h); aggregate 128-dim h per head, then
    // one [N,512] @ [512,128] GEMM with 1/4 folded in. No N*512 xp materialized.
    float* outf = (float*)d_out;
    k_makeWt<<<256, 256, 0, stream>>>(W2, as2, ad2, Wt);
    k_w2p<<<(512 * 128 + 255) / 256, 256, 0, stream>>>(W2, W2p);
    k_attW<<<gw, 256, 0, stream>>>(hbuf, Wt, As, Ad, N);
    k_aggL2<<<gw, 256, 0, stream>>>(hbuf, As, Ad, rowptr, eidx, xp, N);
    k_gemm<128, 512><<<gg1, 256, 0, stream>>>(xp, W2p, outf, N);
    hipMemsetAsync(bns, 0, 256 * 4, stream);
    k_bnstats<<<256, 256, 0, stream>>>(outf, bns, N);
    k_bnapply<<<(N * 32 + 255) / 256, 256, 0, stream>>>(outf, bns, g2v, be2, N, 0);
}